// Round 2
// baseline (409.250 us; speedup 1.0000x reference)
//
#include <hip/hip_runtime.h>
#include <math.h>

#define B_  64
#define T_  1024
#define QD_ 1024
#define CD_ 512

// ---------------------------------------------------------------------------
// Kernel A: normalized attention weights a[b,t]
//   raw = ((1-u)*alpha[t] + u*alpha[t-1] + 1e-6)^sq ;  a = raw / sum_t(raw)
// One block per batch, 256 threads, 4 t's per thread.
// __powf: x > 0 guaranteed (alpha>=0, u in (0,1), +1e-6), so the fast
// exp2(y*log2(x)) path is exact enough (rel err ~1e-5 << 5.8e-2 threshold).
// ---------------------------------------------------------------------------
__global__ __launch_bounds__(256) void attn_alpha_kernel(
    const float* __restrict__ alpha, const float* __restrict__ u,
    const float* __restrict__ sq, float* __restrict__ out_a)
{
    const int b   = blockIdx.x;
    const int tid = threadIdx.x;
    __shared__ float s_alpha[T_];
    __shared__ float s_red[4];

    ((float4*)s_alpha)[tid] = ((const float4*)(alpha + (size_t)b * T_))[tid];
    __syncthreads();

    const float ub  = u[b];
    const float sqb = sq[b];
    const float omu = 1.0f - ub;

    const int t0 = tid * 4;
    float raw[4];
    float lsum = 0.f;
#pragma unroll
    for (int i = 0; i < 4; ++i) {
        const int t = t0 + i;
        const float prev = (t == 0) ? 0.f : s_alpha[t - 1];
        const float x = omu * s_alpha[t] + ub * prev + 1e-6f;
        const float r = __powf(x, sqb);          // x > 0 always
        raw[i] = r;
        lsum += r;
    }
#pragma unroll
    for (int off = 32; off > 0; off >>= 1) lsum += __shfl_down(lsum, off);
    if ((tid & 63) == 0) s_red[tid >> 6] = lsum;
    __syncthreads();
    if (tid == 0) s_red[0] = s_red[0] + s_red[1] + s_red[2] + s_red[3];
    __syncthreads();
    const float inv = 1.0f / s_red[0];

    float4 o;
    o.x = raw[0] * inv; o.y = raw[1] * inv; o.z = raw[2] * inv; o.w = raw[3] * inv;
    ((float4*)(out_a + (size_t)b * T_))[tid] = o;
}

// ---------------------------------------------------------------------------
// Fused kernel B+C: context partials + last-block-per-batch finishes.
// grid = (SEG, B), 128 threads. Thread tid owns float4 lane of CD.
// Writer side: store partial -> __threadfence -> __syncthreads -> atomicAdd.
// The block that sees old == SEG-1 reduces all partials for batch b, writes
// context, and computes both sigmoid heads (rocPRIM-style fence pattern).
// ---------------------------------------------------------------------------
template <int SEG>
__global__ __launch_bounds__(128) void attn_ctx_fused(
    const float* __restrict__ inputs, const float* __restrict__ a,
    const float* __restrict__ query,
    const float* __restrict__ W_u, const float* __restrict__ b_u,
    const float* __restrict__ W_sq, const float* __restrict__ b_sq,
    float* __restrict__ part, unsigned int* __restrict__ cnt,
    float* __restrict__ out_ctx, float* __restrict__ out_u,
    float* __restrict__ out_sq)
{
    constexpr int SLEN = T_ / SEG;
    const int seg = blockIdx.x;
    const int b   = blockIdx.y;
    const int tid = threadIdx.x;

    __shared__ float s_a[SLEN];
    if (tid < SLEN) s_a[tid] = a[(size_t)b * T_ + seg * SLEN + tid];
    __syncthreads();

    const float4* in4 =
        (const float4*)(inputs + ((size_t)b * T_ + (size_t)seg * SLEN) * CD_);

    float4 acc = {0.f, 0.f, 0.f, 0.f};
#pragma unroll 8
    for (int i = 0; i < SLEN; ++i) {
        const float av = s_a[i];
        const float4 x = in4[(size_t)i * 128 + tid];
        acc.x += av * x.x; acc.y += av * x.y; acc.z += av * x.z; acc.w += av * x.w;
    }
    ((float4*)(part + ((size_t)b * SEG + seg) * CD_))[tid] = acc;

    __threadfence();          // make this block's partial visible device-wide
    __syncthreads();          // all threads' stores fenced before the signal
    __shared__ unsigned int s_old;
    if (tid == 0) s_old = atomicAdd(&cnt[b], 1u);
    __syncthreads();
    if (s_old != SEG - 1) return;
    __threadfence();          // acquire: don't read stale partials

    // ---- tail: reduce SEG partials -> context ----
    float4 c = {0.f, 0.f, 0.f, 0.f};
    const float4* p4 = (const float4*)(part + (size_t)b * SEG * CD_);
#pragma unroll 8
    for (int s = 0; s < SEG; ++s) {
        const float4 x = p4[(size_t)s * 128 + tid];
        c.x += x.x; c.y += x.y; c.z += x.z; c.w += x.w;
    }
    ((float4*)(out_ctx + (size_t)b * CD_))[tid] = c;

    // ---- heads: sigmoid(ta . W + b), ta = [context, query] ----
    const float* qb = query + (size_t)b * QD_;
    const int ch = tid * 4;
    float du = c.x * W_u[ch]  + c.y * W_u[ch + 1]  + c.z * W_u[ch + 2]  + c.w * W_u[ch + 3];
    float ds = c.x * W_sq[ch] + c.y * W_sq[ch + 1] + c.z * W_sq[ch + 2] + c.w * W_sq[ch + 3];
#pragma unroll
    for (int j = 0; j < QD_ / 128; ++j) {
        const int q_idx = j * 128 + tid;
        const float q = qb[q_idx];
        du += q * W_u[CD_ + q_idx];
        ds += q * W_sq[CD_ + q_idx];
    }
#pragma unroll
    for (int off = 32; off > 0; off >>= 1) {
        du += __shfl_down(du, off);
        ds += __shfl_down(ds, off);
    }
    __shared__ float s_u[2], s_s[2];
    if ((tid & 63) == 0) { s_u[tid >> 6] = du; s_s[tid >> 6] = ds; }
    __syncthreads();
    if (tid == 0) {
        const float su = s_u[0] + s_u[1] + b_u[0];
        const float ss = s_s[0] + s_s[1] + b_sq[0];
        out_u[b]  = 1.0f / (1.0f + __expf(-su));
        out_sq[b] = 1.0f / (1.0f + __expf(-ss)) + 1.0f;
    }
}

// ---------------------------------------------------------------------------
// Fallback path (only if d_ws is too small — not expected, ws ~512 MB):
// atomic context + separate heads kernel.
// ---------------------------------------------------------------------------
__global__ __launch_bounds__(128) void attn_ctx_atomic(
    const float* __restrict__ inputs, const float* __restrict__ a,
    float* __restrict__ ctx, int S, int seg_len)
{
    const int seg = blockIdx.x;
    const int b   = blockIdx.y;
    const int tid = threadIdx.x;

    __shared__ float s_a[T_];
    const float* ab = a + (size_t)b * T_ + (size_t)seg * seg_len;
    for (int i = tid; i < seg_len; i += 128) s_a[i] = ab[i];
    __syncthreads();

    const float4* in4 =
        (const float4*)(inputs + ((size_t)b * T_ + (size_t)seg * seg_len) * CD_);

    float4 acc = {0.f, 0.f, 0.f, 0.f};
    for (int i = 0; i < seg_len; ++i) {
        const float av = s_a[i];
        const float4 x = in4[(size_t)i * 128 + tid];
        acc.x += av * x.x; acc.y += av * x.y; acc.z += av * x.z; acc.w += av * x.w;
    }
    float* dst = ctx + (size_t)b * CD_ + tid * 4;
    atomicAdd(dst + 0, acc.x);
    atomicAdd(dst + 1, acc.y);
    atomicAdd(dst + 2, acc.z);
    atomicAdd(dst + 3, acc.w);
}

__global__ __launch_bounds__(512) void attn_heads(
    const float* __restrict__ query,
    const float* __restrict__ W_u, const float* __restrict__ b_u,
    const float* __restrict__ W_sq, const float* __restrict__ b_sq,
    const float* __restrict__ out_ctx, float* __restrict__ out_u,
    float* __restrict__ out_sq)
{
    const int b   = blockIdx.x;
    const int tid = threadIdx.x;

    const float c  = out_ctx[(size_t)b * CD_ + tid];
    const float* qb = query + (size_t)b * QD_;
    const float q0 = qb[tid];
    const float q1 = qb[tid + 512];

    float du = c * W_u[tid]  + q0 * W_u[512 + tid]  + q1 * W_u[1024 + tid];
    float ds = c * W_sq[tid] + q0 * W_sq[512 + tid] + q1 * W_sq[1024 + tid];
#pragma unroll
    for (int off = 32; off > 0; off >>= 1) {
        du += __shfl_down(du, off);
        ds += __shfl_down(ds, off);
    }
    __shared__ float s_u[8], s_s[8];
    if ((tid & 63) == 0) { s_u[tid >> 6] = du; s_s[tid >> 6] = ds; }
    __syncthreads();
    if (tid == 0) {
        float su = b_u[0], ss = b_sq[0];
#pragma unroll
        for (int w = 0; w < 8; ++w) { su += s_u[w]; ss += s_s[w]; }
        out_u[b]  = 1.0f / (1.0f + __expf(-su));
        out_sq[b] = 1.0f / (1.0f + __expf(-ss)) + 1.0f;
    }
}

// ---------------------------------------------------------------------------
extern "C" void kernel_launch(void* const* d_in, const int* in_sizes, int n_in,
                              void* d_out, int out_size, void* d_ws, size_t ws_size,
                              hipStream_t stream) {
    const float* query  = (const float*)d_in[0];  // [B,1,QD]
    const float* inputs = (const float*)d_in[1];  // [B,T,CD]
    const float* alpha  = (const float*)d_in[2];  // [B,T]
    const float* u      = (const float*)d_in[3];  // [B,1]
    const float* sq     = (const float*)d_in[4];  // [B,1]
    const float* W_u    = (const float*)d_in[5];  // [QD+CD,1]
    const float* b_u    = (const float*)d_in[6];  // [1]
    const float* W_sq   = (const float*)d_in[7];  // [QD+CD,1]
    const float* b_sq   = (const float*)d_in[8];  // [1]

    float* out      = (float*)d_out;
    float* out_ctx  = out;                         // [B,CD]
    float* out_a    = out + (size_t)B_ * CD_;      // [B,T]
    float* out_u    = out_a + (size_t)B_ * T_;     // [B]
    float* out_sq   = out_u + B_;                  // [B]

    // 1) normalized attention weights
    attn_alpha_kernel<<<B_, 256, 0, stream>>>(alpha, u, sq, out_a);

    constexpr int SEG = 32;
    const size_t part_bytes = (size_t)B_ * SEG * CD_ * sizeof(float);
    const size_t cnt_bytes  = (size_t)B_ * sizeof(unsigned int);

    if (ws_size >= part_bytes + cnt_bytes) {
        float* part        = (float*)d_ws;
        unsigned int* cnt  = (unsigned int*)((char*)d_ws + part_bytes);
        hipMemsetAsync(cnt, 0, cnt_bytes, stream);
        attn_ctx_fused<SEG><<<dim3(SEG, B_), 128, 0, stream>>>(
            inputs, out_a, query, W_u, b_u, W_sq, b_sq,
            part, cnt, out_ctx, out_u, out_sq);
    } else {
        // fallback: atomic accumulation directly into out_ctx
        hipMemsetAsync(out_ctx, 0, (size_t)B_ * CD_ * sizeof(float), stream);
        attn_ctx_atomic<<<dim3(SEG, B_), 128, 0, stream>>>(inputs, out_a, out_ctx, SEG, T_ / SEG);
        attn_heads<<<B_, 512, 0, stream>>>(query, W_u, b_u, W_sq, b_sq,
                                           out_ctx, out_u, out_sq);
    }
}

// Round 3
// 213.875 us; speedup vs baseline: 1.9135x; 1.9135x over previous
//
#include <hip/hip_runtime.h>
#include <math.h>

#define B_  64
#define T_  1024
#define QD_ 1024
#define CD_ 512
#define SEG_ 32              // segments per batch
#define SLEN_ (T_ / SEG_)    // 32 timesteps per block

// ---------------------------------------------------------------------------
// Kernel 1: fused alpha + context partials, NO cross-block communication.
// grid = (SEG, B), 128 threads. Every block redundantly computes the full
// raw[t] = ((1-u)*alpha[t] + u*alpha[t-1] + 1e-6)^sq row and its sum
// (~2K quarter-rate transcendentals, noise vs the 64 KB HBM segment read),
// then emits its segment's NORMALIZED partial context to ws. The seg==0
// block also writes the normalized a row to d_out. Deterministic, fence-free.
// ---------------------------------------------------------------------------
__global__ __launch_bounds__(128) void attn_ctx_all(
    const float* __restrict__ inputs, const float* __restrict__ alpha,
    const float* __restrict__ u, const float* __restrict__ sq,
    float* __restrict__ part, float* __restrict__ out_a)
{
    const int seg = blockIdx.x;
    const int b   = blockIdx.y;
    const int tid = threadIdx.x;

    __shared__ float s_alpha[T_];
    __shared__ float s_raw[T_];
    __shared__ float s_red[2];

    // load alpha row: 1024 floats / 128 threads = 2 float4 each
    {
        const float4* a4 = (const float4*)(alpha + (size_t)b * T_);
        ((float4*)s_alpha)[tid]       = a4[tid];
        ((float4*)s_alpha)[tid + 128] = a4[tid + 128];
    }
    __syncthreads();

    const float ub  = u[b];
    const float sqb = sq[b];
    const float omu = 1.0f - ub;

    // raw + local sum; t = i*128+tid keeps LDS conflict-free
    float lsum = 0.f;
#pragma unroll
    for (int i = 0; i < T_ / 128; ++i) {
        const int t = i * 128 + tid;
        const float prev = (t == 0) ? 0.f : s_alpha[t - 1];
        const float x = omu * s_alpha[t] + ub * prev + 1e-6f;
        const float r = __powf(x, sqb);          // x > 0 always
        s_raw[t] = r;
        lsum += r;
    }
    // block reduce (2 waves)
#pragma unroll
    for (int off = 32; off > 0; off >>= 1) lsum += __shfl_down(lsum, off);
    if ((tid & 63) == 0) s_red[tid >> 6] = lsum;
    __syncthreads();                             // also covers s_raw writes
    const float inv = 1.0f / (s_red[0] + s_red[1]);

    // segment dot: acc += raw[t] * inputs[b,t,:], then scale by inv once
    const float4* in4 =
        (const float4*)(inputs + ((size_t)b * T_ + (size_t)seg * SLEN_) * CD_);
    float4 acc = {0.f, 0.f, 0.f, 0.f};
#pragma unroll 8
    for (int i = 0; i < SLEN_; ++i) {
        const float av = s_raw[seg * SLEN_ + i];
        const float4 x = in4[(size_t)i * 128 + tid];
        acc.x += av * x.x; acc.y += av * x.y; acc.z += av * x.z; acc.w += av * x.w;
    }
    acc.x *= inv; acc.y *= inv; acc.z *= inv; acc.w *= inv;
    ((float4*)(part + ((size_t)b * SEG_ + seg) * CD_))[tid] = acc;

    // seg 0 writes the normalized attention weights
    if (seg == 0) {
#pragma unroll
        for (int j = 0; j < 2; ++j) {
            const float4 r = ((const float4*)s_raw)[j * 128 + tid];
            float4 o;
            o.x = r.x * inv; o.y = r.y * inv; o.z = r.z * inv; o.w = r.w * inv;
            ((float4*)(out_a + (size_t)b * T_))[j * 128 + tid] = o;
        }
    }
}

// ---------------------------------------------------------------------------
// Kernel 2: reduce partials -> context; two 1536-element sigmoid heads.
// One block per batch, 512 threads (thread == context channel).
// ---------------------------------------------------------------------------
__global__ __launch_bounds__(512) void attn_final(
    const float* __restrict__ part,
    const float* __restrict__ query,
    const float* __restrict__ W_u, const float* __restrict__ b_u,
    const float* __restrict__ W_sq, const float* __restrict__ b_sq,
    float* __restrict__ out_ctx, float* __restrict__ out_u,
    float* __restrict__ out_sq)
{
    const int b   = blockIdx.x;
    const int tid = threadIdx.x;   // 0..511 == context channel

    float c = 0.f;
    const float* pb = part + (size_t)b * SEG_ * CD_;
#pragma unroll 8
    for (int s = 0; s < SEG_; ++s) c += pb[(size_t)s * CD_ + tid];
    out_ctx[(size_t)b * CD_ + tid] = c;

    const float* qb = query + (size_t)b * QD_;
    const float q0 = qb[tid];
    const float q1 = qb[tid + 512];

    float du = c * W_u[tid]  + q0 * W_u[512 + tid]  + q1 * W_u[1024 + tid];
    float ds = c * W_sq[tid] + q0 * W_sq[512 + tid] + q1 * W_sq[1024 + tid];
#pragma unroll
    for (int off = 32; off > 0; off >>= 1) {
        du += __shfl_down(du, off);
        ds += __shfl_down(ds, off);
    }
    __shared__ float s_u[8], s_s[8];
    if ((tid & 63) == 0) { s_u[tid >> 6] = du; s_s[tid >> 6] = ds; }
    __syncthreads();
    if (tid == 0) {
        float su = b_u[0], ss = b_sq[0];
#pragma unroll
        for (int w = 0; w < 8; ++w) { su += s_u[w]; ss += s_s[w]; }
        out_u[b]  = 1.0f / (1.0f + __expf(-su));
        out_sq[b] = 1.0f / (1.0f + __expf(-ss)) + 1.0f;
    }
}

// ---------------------------------------------------------------------------
// Fallback (ws too small — not expected): atomics into out_ctx + heads.
// ---------------------------------------------------------------------------
__global__ __launch_bounds__(128) void attn_ctx_atomic(
    const float* __restrict__ inputs, const float* __restrict__ alpha,
    const float* __restrict__ u, const float* __restrict__ sq,
    float* __restrict__ ctx, float* __restrict__ out_a)
{
    const int seg = blockIdx.x;
    const int b   = blockIdx.y;
    const int tid = threadIdx.x;

    __shared__ float s_alpha[T_];
    __shared__ float s_raw[T_];
    __shared__ float s_red[2];

    const float4* a4 = (const float4*)(alpha + (size_t)b * T_);
    ((float4*)s_alpha)[tid]       = a4[tid];
    ((float4*)s_alpha)[tid + 128] = a4[tid + 128];
    __syncthreads();

    const float ub  = u[b];
    const float sqb = sq[b];
    const float omu = 1.0f - ub;

    float lsum = 0.f;
#pragma unroll
    for (int i = 0; i < T_ / 128; ++i) {
        const int t = i * 128 + tid;
        const float prev = (t == 0) ? 0.f : s_alpha[t - 1];
        const float x = omu * s_alpha[t] + ub * prev + 1e-6f;
        const float r = __powf(x, sqb);
        s_raw[t] = r;
        lsum += r;
    }
#pragma unroll
    for (int off = 32; off > 0; off >>= 1) lsum += __shfl_down(lsum, off);
    if ((tid & 63) == 0) s_red[tid >> 6] = lsum;
    __syncthreads();
    const float inv = 1.0f / (s_red[0] + s_red[1]);

    const float4* in4 =
        (const float4*)(inputs + ((size_t)b * T_ + (size_t)seg * SLEN_) * CD_);
    float4 acc = {0.f, 0.f, 0.f, 0.f};
    for (int i = 0; i < SLEN_; ++i) {
        const float av = s_raw[seg * SLEN_ + i];
        const float4 x = in4[(size_t)i * 128 + tid];
        acc.x += av * x.x; acc.y += av * x.y; acc.z += av * x.z; acc.w += av * x.w;
    }
    float* dst = ctx + (size_t)b * CD_ + tid * 4;
    atomicAdd(dst + 0, acc.x * inv);
    atomicAdd(dst + 1, acc.y * inv);
    atomicAdd(dst + 2, acc.z * inv);
    atomicAdd(dst + 3, acc.w * inv);

    if (seg == 0) {
#pragma unroll
        for (int j = 0; j < 2; ++j) {
            const float4 r = ((const float4*)s_raw)[j * 128 + tid];
            float4 o;
            o.x = r.x * inv; o.y = r.y * inv; o.z = r.z * inv; o.w = r.w * inv;
            ((float4*)(out_a + (size_t)b * T_))[j * 128 + tid] = o;
        }
    }
}

__global__ __launch_bounds__(512) void attn_heads(
    const float* __restrict__ query,
    const float* __restrict__ W_u, const float* __restrict__ b_u,
    const float* __restrict__ W_sq, const float* __restrict__ b_sq,
    const float* __restrict__ out_ctx, float* __restrict__ out_u,
    float* __restrict__ out_sq)
{
    const int b   = blockIdx.x;
    const int tid = threadIdx.x;

    const float c  = out_ctx[(size_t)b * CD_ + tid];
    const float* qb = query + (size_t)b * QD_;
    const float q0 = qb[tid];
    const float q1 = qb[tid + 512];

    float du = c * W_u[tid]  + q0 * W_u[512 + tid]  + q1 * W_u[1024 + tid];
    float ds = c * W_sq[tid] + q0 * W_sq[512 + tid] + q1 * W_sq[1024 + tid];
#pragma unroll
    for (int off = 32; off > 0; off >>= 1) {
        du += __shfl_down(du, off);
        ds += __shfl_down(ds, off);
    }
    __shared__ float s_u[8], s_s[8];
    if ((tid & 63) == 0) { s_u[tid >> 6] = du; s_s[tid >> 6] = ds; }
    __syncthreads();
    if (tid == 0) {
        float su = b_u[0], ss = b_sq[0];
#pragma unroll
        for (int w = 0; w < 8; ++w) { su += s_u[w]; ss += s_s[w]; }
        out_u[b]  = 1.0f / (1.0f + __expf(-su));
        out_sq[b] = 1.0f / (1.0f + __expf(-ss)) + 1.0f;
    }
}

// ---------------------------------------------------------------------------
extern "C" void kernel_launch(void* const* d_in, const int* in_sizes, int n_in,
                              void* d_out, int out_size, void* d_ws, size_t ws_size,
                              hipStream_t stream) {
    const float* query  = (const float*)d_in[0];  // [B,1,QD]
    const float* inputs = (const float*)d_in[1];  // [B,T,CD]
    const float* alpha  = (const float*)d_in[2];  // [B,T]
    const float* u      = (const float*)d_in[3];  // [B,1]
    const float* sq     = (const float*)d_in[4];  // [B,1]
    const float* W_u    = (const float*)d_in[5];  // [QD+CD,1]
    const float* b_u    = (const float*)d_in[6];  // [1]
    const float* W_sq   = (const float*)d_in[7];  // [QD+CD,1]
    const float* b_sq   = (const float*)d_in[8];  // [1]

    float* out      = (float*)d_out;
    float* out_ctx  = out;                         // [B,CD]
    float* out_a    = out + (size_t)B_ * CD_;      // [B,T]
    float* out_u    = out_a + (size_t)B_ * T_;     // [B]
    float* out_sq   = out_u + B_;                  // [B]

    const size_t part_bytes = (size_t)B_ * SEG_ * CD_ * sizeof(float);

    if (ws_size >= part_bytes) {
        float* part = (float*)d_ws;
        attn_ctx_all<<<dim3(SEG_, B_), 128, 0, stream>>>(
            inputs, alpha, u, sq, part, out_a);
        attn_final<<<B_, 512, 0, stream>>>(
            part, query, W_u, b_u, W_sq, b_sq, out_ctx, out_u, out_sq);
    } else {
        hipMemsetAsync(out_ctx, 0, (size_t)B_ * CD_ * sizeof(float), stream);
        attn_ctx_atomic<<<dim3(SEG_, B_), 128, 0, stream>>>(
            inputs, alpha, u, sq, out_ctx, out_a);
        attn_heads<<<B_, 512, 0, stream>>>(
            query, W_u, b_u, W_sq, b_sq, out_ctx, out_u, out_sq);
    }
}

// Round 5
// 201.623 us; speedup vs baseline: 2.0298x; 1.0608x over previous
//
#include <hip/hip_runtime.h>
#include <math.h>

#define B_  64
#define T_  1024
#define QD_ 1024
#define CD_ 512
#define SEGROWS_ 32          // partial rows per batch (layout for final kernel)
#define NBLK_ 16             // ctx blocks per batch; each covers 64 timesteps

// native vector type: __builtin_nontemporal_load requires scalar/ext-vector,
// not HIP_vector_type<float,4>
typedef float floatx4 __attribute__((ext_vector_type(4)));

// ---------------------------------------------------------------------------
// Kernel 1: fused alpha + context partials, fence-free.
// grid = (NBLK_=16, B), 256 threads. Each block redundantly computes the full
// raw[t] = ((1-u)*alpha[t] + u*alpha[t-1] + 1e-6)^sq row and its sum (cheap:
// 4 __powf/thread), then streams its 64-timestep segment of inputs (128 KB,
// nontemporal — read exactly once) into two normalized partial context rows
// (half = tid>>7 owns 32 timesteps). seg==0 block also writes normalized a.
// ---------------------------------------------------------------------------
__global__ __launch_bounds__(256) void attn_ctx_all(
    const float* __restrict__ inputs, const float* __restrict__ alpha,
    const float* __restrict__ u, const float* __restrict__ sq,
    float* __restrict__ part, float* __restrict__ out_a)
{
    const int seg = blockIdx.x;      // 0..15
    const int b   = blockIdx.y;
    const int tid = threadIdx.x;     // 0..255

    __shared__ float s_alpha[T_];
    __shared__ float s_raw[T_];
    __shared__ float s_red[4];

    // alpha row: 1024 floats / 256 threads = 1 float4 each
    ((float4*)s_alpha)[tid] = ((const float4*)(alpha + (size_t)b * T_))[tid];
    __syncthreads();

    const float ub  = u[b];
    const float sqb = sq[b];
    const float omu = 1.0f - ub;

    // raw + local sum (thread owns t in [4*tid, 4*tid+4))
    float lsum = 0.f;
    float rr[4];
    const int t0 = tid * 4;
#pragma unroll
    for (int i = 0; i < 4; ++i) {
        const int t = t0 + i;
        const float prev = (t == 0) ? 0.f : s_alpha[t - 1];
        const float x = omu * s_alpha[t] + ub * prev + 1e-6f;
        const float r = __powf(x, sqb);          // x > 0 always
        rr[i] = r;
        lsum += r;
    }
    {
        float4 w; w.x = rr[0]; w.y = rr[1]; w.z = rr[2]; w.w = rr[3];
        ((float4*)s_raw)[tid] = w;
    }
    // block reduce (4 waves)
#pragma unroll
    for (int off = 32; off > 0; off >>= 1) lsum += __shfl_down(lsum, off);
    if ((tid & 63) == 0) s_red[tid >> 6] = lsum;
    __syncthreads();                             // also covers s_raw writes
    const float inv = 1.0f / (s_red[0] + s_red[1] + s_red[2] + s_red[3]);

    // segment dot: half h owns timesteps [seg*64 + h*32, +32)
    const int lane  = tid & 127;                 // float4 channel of CD
    const int half  = tid >> 7;                  // 0/1
    const int tbase = seg * 64 + half * 32;

    const floatx4* in4 =
        (const floatx4*)(inputs + ((size_t)b * T_ + tbase) * CD_);
    float4 acc = {0.f, 0.f, 0.f, 0.f};
#pragma unroll 8
    for (int i = 0; i < 32; ++i) {
        const float av = s_raw[tbase + i];
        const floatx4 x = __builtin_nontemporal_load(&in4[(size_t)i * 128 + lane]);
        acc.x += av * x.x; acc.y += av * x.y; acc.z += av * x.z; acc.w += av * x.w;
    }
    acc.x *= inv; acc.y *= inv; acc.z *= inv; acc.w *= inv;

    const int prow = seg * 2 + half;             // 0..31, same layout as before
    ((float4*)(part + ((size_t)b * SEGROWS_ + prow) * CD_))[lane] = acc;

    // seg 0 writes the normalized attention weights (1 float4 per thread)
    if (seg == 0) {
        float4 o;
        o.x = rr[0] * inv; o.y = rr[1] * inv; o.z = rr[2] * inv; o.w = rr[3] * inv;
        ((float4*)(out_a + (size_t)b * T_))[tid] = o;
    }
}

// ---------------------------------------------------------------------------
// Kernel 2: reduce partials -> context; two 1536-element sigmoid heads.
// One block per batch, 512 threads (thread == context channel).
// ---------------------------------------------------------------------------
__global__ __launch_bounds__(512) void attn_final(
    const float* __restrict__ part,
    const float* __restrict__ query,
    const float* __restrict__ W_u, const float* __restrict__ b_u,
    const float* __restrict__ W_sq, const float* __restrict__ b_sq,
    float* __restrict__ out_ctx, float* __restrict__ out_u,
    float* __restrict__ out_sq)
{
    const int b   = blockIdx.x;
    const int tid = threadIdx.x;   // 0..511 == context channel

    float c = 0.f;
    const float* pb = part + (size_t)b * SEGROWS_ * CD_;
#pragma unroll 8
    for (int s = 0; s < SEGROWS_; ++s) c += pb[(size_t)s * CD_ + tid];
    out_ctx[(size_t)b * CD_ + tid] = c;

    const float* qb = query + (size_t)b * QD_;
    const float q0 = qb[tid];
    const float q1 = qb[tid + 512];

    float du = c * W_u[tid]  + q0 * W_u[512 + tid]  + q1 * W_u[1024 + tid];
    float ds = c * W_sq[tid] + q0 * W_sq[512 + tid] + q1 * W_sq[1024 + tid];
#pragma unroll
    for (int off = 32; off > 0; off >>= 1) {
        du += __shfl_down(du, off);
        ds += __shfl_down(ds, off);
    }
    __shared__ float s_u[8], s_s[8];
    if ((tid & 63) == 0) { s_u[tid >> 6] = du; s_s[tid >> 6] = ds; }
    __syncthreads();
    if (tid == 0) {
        float su = b_u[0], ss = b_sq[0];
#pragma unroll
        for (int w = 0; w < 8; ++w) { su += s_u[w]; ss += s_s[w]; }
        out_u[b]  = 1.0f / (1.0f + __expf(-su));
        out_sq[b] = 1.0f / (1.0f + __expf(-ss)) + 1.0f;
    }
}

// ---------------------------------------------------------------------------
// Fallback (ws too small — not expected, ws ~512 MB): atomics + heads.
// ---------------------------------------------------------------------------
__global__ __launch_bounds__(256) void attn_ctx_atomic(
    const float* __restrict__ inputs, const float* __restrict__ alpha,
    const float* __restrict__ u, const float* __restrict__ sq,
    float* __restrict__ ctx, float* __restrict__ out_a)
{
    const int seg = blockIdx.x;
    const int b   = blockIdx.y;
    const int tid = threadIdx.x;

    __shared__ float s_alpha[T_];
    __shared__ float s_raw[T_];
    __shared__ float s_red[4];

    ((float4*)s_alpha)[tid] = ((const float4*)(alpha + (size_t)b * T_))[tid];
    __syncthreads();

    const float ub  = u[b];
    const float sqb = sq[b];
    const float omu = 1.0f - ub;

    float lsum = 0.f;
    float rr[4];
    const int t0 = tid * 4;
#pragma unroll
    for (int i = 0; i < 4; ++i) {
        const int t = t0 + i;
        const float prev = (t == 0) ? 0.f : s_alpha[t - 1];
        const float x = omu * s_alpha[t] + ub * prev + 1e-6f;
        const float r = __powf(x, sqb);
        rr[i] = r; lsum += r;
    }
    {
        float4 w; w.x = rr[0]; w.y = rr[1]; w.z = rr[2]; w.w = rr[3];
        ((float4*)s_raw)[tid] = w;
    }
#pragma unroll
    for (int off = 32; off > 0; off >>= 1) lsum += __shfl_down(lsum, off);
    if ((tid & 63) == 0) s_red[tid >> 6] = lsum;
    __syncthreads();
    const float inv = 1.0f / (s_red[0] + s_red[1] + s_red[2] + s_red[3]);

    const int lane  = tid & 127;
    const int half  = tid >> 7;
    const int tbase = seg * 64 + half * 32;

    const float4* in4 =
        (const float4*)(inputs + ((size_t)b * T_ + tbase) * CD_);
    float4 acc = {0.f, 0.f, 0.f, 0.f};
    for (int i = 0; i < 32; ++i) {
        const float av = s_raw[tbase + i];
        const float4 x = in4[(size_t)i * 128 + lane];
        acc.x += av * x.x; acc.y += av * x.y; acc.z += av * x.z; acc.w += av * x.w;
    }
    float* dst = ctx + (size_t)b * CD_ + lane * 4;
    atomicAdd(dst + 0, acc.x * inv);
    atomicAdd(dst + 1, acc.y * inv);
    atomicAdd(dst + 2, acc.z * inv);
    atomicAdd(dst + 3, acc.w * inv);

    if (seg == 0) {
        float4 o;
        o.x = rr[0] * inv; o.y = rr[1] * inv; o.z = rr[2] * inv; o.w = rr[3] * inv;
        ((float4*)(out_a + (size_t)b * T_))[tid] = o;
    }
}

__global__ __launch_bounds__(512) void attn_heads(
    const float* __restrict__ query,
    const float* __restrict__ W_u, const float* __restrict__ b_u,
    const float* __restrict__ W_sq, const float* __restrict__ b_sq,
    const float* __restrict__ out_ctx, float* __restrict__ out_u,
    float* __restrict__ out_sq)
{
    const int b   = blockIdx.x;
    const int tid = threadIdx.x;

    const float c  = out_ctx[(size_t)b * CD_ + tid];
    const float* qb = query + (size_t)b * QD_;
    const float q0 = qb[tid];
    const float q1 = qb[tid + 512];

    float du = c * W_u[tid]  + q0 * W_u[512 + tid]  + q1 * W_u[1024 + tid];
    float ds = c * W_sq[tid] + q0 * W_sq[512 + tid] + q1 * W_sq[1024 + tid];
#pragma unroll
    for (int off = 32; off > 0; off >>= 1) {
        du += __shfl_down(du, off);
        ds += __shfl_down(ds, off);
    }
    __shared__ float s_u[8], s_s[8];
    if ((tid & 63) == 0) { s_u[tid >> 6] = du; s_s[tid >> 6] = ds; }
    __syncthreads();
    if (tid == 0) {
        float su = b_u[0], ss = b_sq[0];
#pragma unroll
        for (int w = 0; w < 8; ++w) { su += s_u[w]; ss += s_s[w]; }
        out_u[b]  = 1.0f / (1.0f + __expf(-su));
        out_sq[b] = 1.0f / (1.0f + __expf(-ss)) + 1.0f;
    }
}

// ---------------------------------------------------------------------------
extern "C" void kernel_launch(void* const* d_in, const int* in_sizes, int n_in,
                              void* d_out, int out_size, void* d_ws, size_t ws_size,
                              hipStream_t stream) {
    const float* query  = (const float*)d_in[0];  // [B,1,QD]
    const float* inputs = (const float*)d_in[1];  // [B,T,CD]
    const float* alpha  = (const float*)d_in[2];  // [B,T]
    const float* u      = (const float*)d_in[3];  // [B,1]
    const float* sq     = (const float*)d_in[4];  // [B,1]
    const float* W_u    = (const float*)d_in[5];  // [QD+CD,1]
    const float* b_u    = (const float*)d_in[6];  // [1]
    const float* W_sq   = (const float*)d_in[7];  // [QD+CD,1]
    const float* b_sq   = (const float*)d_in[8];  // [1]

    float* out      = (float*)d_out;
    float* out_ctx  = out;                         // [B,CD]
    float* out_a    = out + (size_t)B_ * CD_;      // [B,T]
    float* out_u    = out_a + (size_t)B_ * T_;     // [B]
    float* out_sq   = out_u + B_;                  // [B]

    const size_t part_bytes = (size_t)B_ * SEGROWS_ * CD_ * sizeof(float);

    if (ws_size >= part_bytes) {
        float* part = (float*)d_ws;
        attn_ctx_all<<<dim3(NBLK_, B_), 256, 0, stream>>>(
            inputs, alpha, u, sq, part, out_a);
        attn_final<<<B_, 512, 0, stream>>>(
            part, query, W_u, b_u, W_sq, b_sq, out_ctx, out_u, out_sq);
    } else {
        (void)hipMemsetAsync(out_ctx, 0, (size_t)B_ * CD_ * sizeof(float), stream);
        attn_ctx_atomic<<<dim3(NBLK_, B_), 256, 0, stream>>>(
            inputs, alpha, u, sq, out_ctx, out_a);
        attn_heads<<<B_, 512, 0, stream>>>(
            query, W_u, b_u, W_sq, b_sq, out_ctx, out_u, out_sq);
    }
}